// Round 1
// 1422.974 us; speedup vs baseline: 1.4537x; 1.4537x over previous
//
#include <hip/hip_runtime.h>

// Problem constants (match reference: N, M, D = 2048, 2048, 8)
#define PN 2048
#define PM 2048
#define PD 8

// Output layout (flat, fp32, concatenated in return order):
//   cov   : [N*M]        offset 0
//   dx    : [N*M*D]      offset N*M
//   dxx   : [N*M*D]      offset N*M + N*M*D
//   dxdxx : [N*M*D*D]    offset N*M + 2*N*M*D
// Total = 2048*2048*81 floats (~1.36 GB) -> pure streaming-write bound.
//
// Key change vs previous version: every wave store instruction writes a
// CONTIGUOUS 1 KB span (lane l owns float4 chunk base+l). Previous version's
// thread-owns-256B layout scattered 16 B partial writes across 64 cache
// lines per instruction -> RFO fetch (1.3 GB) + 2.9x write amplification
// (3.9 GB HBM writes for a 1.36 GB output). VALU was 1.6% busy, so lanes
// recompute their pair instead of owning it.

#define NM_TOT   (PN * PM)                 // 4,194,304 pairs
#define BLOCKS_A (NM_TOT * 16 / 256)       // dxdxx float4 chunks / 256 = 262,144
#define BLOCKS_B (NM_TOT * 2 / 256)        // dx (and dxx) float4 chunks = 32,768
#define BLOCKS_C (NM_TOT / 256)            // cov scalar = 16,384

// ws layout: ws[0..7] = iscale, ws[8] = variance, ws[9..16] = iscale^2
__global__ void rbf_precompute(const float* __restrict__ scale_free,
                               const float* __restrict__ var_free,
                               float* __restrict__ ws) {
    const int t = threadIdx.x;
    if (t < PD) {
        const float is = __expf(-scale_free[t]);
        ws[t]     = is;
        ws[9 + t] = is * is;
    }
    if (t == PD) ws[8] = __expf(var_free[0]);
}

__global__ __launch_bounds__(256) void rbf_all_kernel(
    const float* __restrict__ x,   // [N, D]
    const float* __restrict__ xx,  // [M, D]
    const float* __restrict__ ws,  // iscale[8], variance, iscale2[8]
    float* __restrict__ out)
{
    const unsigned tid = threadIdx.x;
    const unsigned bid = blockIdx.x;

    float is[PD], is2[PD];
#pragma unroll
    for (int d = 0; d < PD; ++d) { is[d] = ws[d]; is2[d] = ws[9 + d]; }
    const float variance = ws[8];

    const size_t NM = (size_t)PN * PM;
    float* covp   = out;
    float* dxp    = out + NM;
    float* dxxp   = out + NM + NM * PD;
    float* dxdxxp = out + NM + 2 * NM * PD;

    // Computes r[8] and cov for pair p. 16 floats of input; rows are 32 B
    // aligned; x/xx are 64 KB each -> L1/L2 resident, lanes sharing p
    // broadcast-coalesce.
    auto compute_pair = [&](unsigned p, float r[PD]) -> float {
        const unsigned n = p >> 11;     // p / M
        const unsigned m = p & 2047u;   // p % M
        const float4* x4  = reinterpret_cast<const float4*>(x  + (size_t)n * PD);
        const float4* xx4 = reinterpret_cast<const float4*>(xx + (size_t)m * PD);
        const float4 xa = x4[0],  xb = x4[1];
        const float4 ya = xx4[0], yb = xx4[1];
        r[0] = (xa.x - ya.x) * is[0];
        r[1] = (xa.y - ya.y) * is[1];
        r[2] = (xa.z - ya.z) * is[2];
        r[3] = (xa.w - ya.w) * is[3];
        r[4] = (xb.x - yb.x) * is[4];
        r[5] = (xb.y - yb.y) * is[5];
        r[6] = (xb.z - yb.z) * is[6];
        r[7] = (xb.w - yb.w) * is[7];
        float s = 0.f;
#pragma unroll
        for (int d = 0; d < PD; ++d) s += r[d] * r[d];
        return __expf(-0.5f * s) * variance;
    };

    if (bid < BLOCKS_A) {
        // ---- dxdxx: one float4 chunk per lane, lane-contiguous stores ----
        // chunk g covers dxdxx floats [g*4, g*4+4); pair p = g>>4, i = g&15
        // element e = i*4 + j  ->  row = e>>3 = i>>1, col = e&7 = (i&1)*4 + j
        const unsigned g = bid * 256u + tid;
        const unsigned p = g >> 4;
        const unsigned i = g & 15u;
        float r[PD];
        const float cov = compute_pair(p, r);
        float rr[PD];
#pragma unroll
        for (int d = 0; d < PD; ++d) rr[d] = r[d] * is[d];

        const unsigned row = i >> 1;
        const unsigned c0  = (i & 1u) * 4u;
        const float a = -cov * rr[row];
        float v[4];
#pragma unroll
        for (int j = 0; j < 4; ++j) v[j] = a * rr[c0 + j];
        // diagonal term: col == row lands in this chunk iff row in [c0, c0+4)
        if (row >= c0 && row < c0 + 4u) v[row - c0] += cov * is2[row];

        float4* d2 = reinterpret_cast<float4*>(dxdxxp + (size_t)g * 4);
        *d2 = make_float4(v[0], v[1], v[2], v[3]);
    } else if (bid < BLOCKS_A + BLOCKS_B) {
        // ---- dx and dxx: one float4 chunk per lane for each array ----
        // chunk g covers floats [g*4, g*4+4); pair p = g>>1, half i = g&1
        const unsigned g = (bid - BLOCKS_A) * 256u + tid;
        const unsigned p = g >> 1;
        const unsigned c0 = (g & 1u) * 4u;
        float r[PD];
        const float cov = compute_pair(p, r);
        float w[4];
#pragma unroll
        for (int j = 0; j < 4; ++j) w[j] = cov * r[c0 + j] * is[c0 + j];

        float4* ddx  = reinterpret_cast<float4*>(dxp  + (size_t)g * 4);
        float4* ddxx = reinterpret_cast<float4*>(dxxp + (size_t)g * 4);
        *ddx  = make_float4(-w[0], -w[1], -w[2], -w[3]);
        *ddxx = make_float4( w[0],  w[1],  w[2],  w[3]);
    } else {
        // ---- cov: one pair per lane, scalar coalesced store ----
        const unsigned p = (bid - BLOCKS_A - BLOCKS_B) * 256u + tid;
        float r[PD];
        covp[p] = compute_pair(p, r);
    }
}

extern "C" void kernel_launch(void* const* d_in, const int* in_sizes, int n_in,
                              void* d_out, int out_size, void* d_ws, size_t ws_size,
                              hipStream_t stream) {
    const float* x  = (const float*)d_in[0];
    const float* xx = (const float*)d_in[1];
    const float* sf = (const float*)d_in[2];
    const float* vf = (const float*)d_in[3];
    float* out = (float*)d_out;
    float* ws  = (float*)d_ws;

    rbf_precompute<<<1, 64, 0, stream>>>(sf, vf, ws);

    const int grid = BLOCKS_A + BLOCKS_B + BLOCKS_C;  // 311,296 blocks
    rbf_all_kernel<<<grid, 256, 0, stream>>>(x, xx, ws, out);
}

// Round 2
// 1316.886 us; speedup vs baseline: 1.5708x; 1.0806x over previous
//
#include <hip/hip_runtime.h>

// Problem constants (match reference: N, M, D = 2048, 2048, 8)
#define PN 2048
#define PM 2048
#define PD 8

#define NM ((size_t)PN * (size_t)PM)

// Output layout (flat, fp32, concatenated in return order):
//   cov   : [N*M]        offset 0
//   dx    : [N*M*D]      offset N*M
//   dxx   : [N*M*D]      offset N*M + N*M*D
//   dxdxx : [N*M*D*D]    offset N*M + 2*N*M*D
// Total = 2048*2048*81 floats (~1.36 GB) -> pure streaming-write bound.
//
// Structure: one block owns 256 consecutive pairs.
//   Phase 1 (compute): thread t computes pair p = bid*256+t once
//     (xx-row loads perfectly coalesced across threads, x-row broadcast),
//     parks rr[8]+cov in LDS (stride 12 floats, float4-aligned).
//   Phase 2 (stream): block writes its whole 83 KB output region with
//     every wave store instruction covering a contiguous, 1KB-aligned span
//     (full 128B lines per instruction -> no read-for-ownership), and each
//     thread issuing 21 independent stores (deep store queue, fill-kernel
//     style). This removes both the 19x pair recompute and the residual
//     stride-32B half-line pattern dx/dxx had.

// ws layout: ws[0..7] = iscale, ws[8] = variance, ws[9..16] = iscale^2
__global__ void rbf_precompute(const float* __restrict__ scale_free,
                               const float* __restrict__ var_free,
                               float* __restrict__ ws) {
    const int t = threadIdx.x;
    if (t < PD) {
        const float is = __expf(-scale_free[t]);
        ws[t]     = is;
        ws[9 + t] = is * is;
    }
    if (t == PD) ws[8] = __expf(var_free[0]);
}

__global__ __launch_bounds__(256) void rbf_all_kernel(
    const float* __restrict__ x,   // [N, D]
    const float* __restrict__ xx,  // [M, D]
    const float* __restrict__ ws,  // iscale[8], variance, iscale2[8]
    float* __restrict__ out)
{
    // per local pair q: lds[q*12 + 0..7] = rr, lds[q*12 + 8] = cov (3 pad)
    __shared__ __align__(16) float lds[256 * 12];

    const unsigned tid = threadIdx.x;
    const unsigned bid = blockIdx.x;

    float is[PD];
#pragma unroll
    for (int d = 0; d < PD; ++d) is[d] = ws[d];
    const float variance = ws[8];

    float* covp   = out;
    float* dxp    = out + NM;
    float* dxxp   = out + NM + NM * PD;
    float* dxdxxp = out + NM + 2 * NM * PD;

    // ---- Phase 1: compute own pair, park in LDS ----
    const unsigned p = bid * 256u + tid;
    const unsigned n = p >> 11;      // uniform across the block (256 | 2048)
    const unsigned m = p & 2047u;    // consecutive across threads -> coalesced
    const float4* x4  = reinterpret_cast<const float4*>(x  + (size_t)n * PD);
    const float4* xx4 = reinterpret_cast<const float4*>(xx + (size_t)m * PD);
    const float4 xa = x4[0],  xb = x4[1];
    const float4 ya = xx4[0], yb = xx4[1];

    float r[PD];
    r[0] = (xa.x - ya.x) * is[0];
    r[1] = (xa.y - ya.y) * is[1];
    r[2] = (xa.z - ya.z) * is[2];
    r[3] = (xa.w - ya.w) * is[3];
    r[4] = (xb.x - yb.x) * is[4];
    r[5] = (xb.y - yb.y) * is[5];
    r[6] = (xb.z - yb.z) * is[6];
    r[7] = (xb.w - yb.w) * is[7];

    float s = 0.f;
#pragma unroll
    for (int d = 0; d < PD; ++d) s += r[d] * r[d];
    const float cov = __expf(-0.5f * s) * variance;

    float rr[PD];
#pragma unroll
    for (int d = 0; d < PD; ++d) rr[d] = r[d] * is[d];

    float4* lrow = reinterpret_cast<float4*>(&lds[tid * 12u]);
    lrow[0] = make_float4(rr[0], rr[1], rr[2], rr[3]);
    lrow[1] = make_float4(rr[4], rr[5], rr[6], rr[7]);
    lds[tid * 12u + 8u] = cov;

    // cov: 64 contiguous floats per wave store -> full lines
    covp[p] = cov;

    __syncthreads();

    // ---- Phase 2a: dx / dxx — 2 float4 chunks per thread, lane-contiguous ----
    // block dx region = floats [bid*2048, +2048) = chunks [0,512)
    // chunk c2: pair q = c2>>1, components [c0, c0+4)
#pragma unroll
    for (int s2 = 0; s2 < 2; ++s2) {
        const unsigned c2 = (unsigned)s2 * 256u + tid;
        const unsigned q  = c2 >> 1;
        const unsigned c0 = (c2 & 1u) * 4u;
        const float4 rr4 = *reinterpret_cast<const float4*>(&lds[q * 12u + c0]);
        const float covq = lds[q * 12u + 8u];
        const float4 w = make_float4(covq * rr4.x, covq * rr4.y,
                                     covq * rr4.z, covq * rr4.w);
        const size_t off = (size_t)bid * 2048u + (size_t)c2 * 4u;
        *reinterpret_cast<float4*>(dxp  + off) = make_float4(-w.x, -w.y, -w.z, -w.w);
        *reinterpret_cast<float4*>(dxxp + off) = w;
    }

    // ---- Phase 2b: dxdxx — 16 float4 chunks per thread, lane-contiguous ----
    // block region = floats [bid*16384, +16384) = chunks [0,4096)
    // chunk c = s1*256 + tid: pair q = c>>4; element e = (c&15)*4 + j
    //   -> row i = (tid&15)>>1, col = (tid&1)*4 + j  (per-lane constants)
    const unsigned t15  = tid & 15u;
    const unsigned row  = t15 >> 1;
    const unsigned c0d  = (t15 & 1u) * 4u;
    const int dcol = (int)row - (int)c0d;        // diag hits v[dcol] if in [0,4)
    const float is2row = ws[9u + row];           // from memory: no runtime reg-index
    const unsigned qbase = tid >> 4;

#pragma unroll
    for (int s1 = 0; s1 < 16; ++s1) {
        const unsigned q = (unsigned)s1 * 16u + qbase;
        const float4 rr4 = *reinterpret_cast<const float4*>(&lds[q * 12u + c0d]);
        const float rrow = lds[q * 12u + row];
        const float covq = lds[q * 12u + 8u];
        const float a = -covq * rrow;
        float4 v = make_float4(a * rr4.x, a * rr4.y, a * rr4.z, a * rr4.w);
        const float dadd = covq * is2row;
        v.x += (dcol == 0) ? dadd : 0.f;
        v.y += (dcol == 1) ? dadd : 0.f;
        v.z += (dcol == 2) ? dadd : 0.f;
        v.w += (dcol == 3) ? dadd : 0.f;
        const unsigned c = (unsigned)s1 * 256u + tid;
        *reinterpret_cast<float4*>(dxdxxp + (size_t)bid * 16384u + (size_t)c * 4u) = v;
    }
}

extern "C" void kernel_launch(void* const* d_in, const int* in_sizes, int n_in,
                              void* d_out, int out_size, void* d_ws, size_t ws_size,
                              hipStream_t stream) {
    const float* x  = (const float*)d_in[0];
    const float* xx = (const float*)d_in[1];
    const float* sf = (const float*)d_in[2];
    const float* vf = (const float*)d_in[3];
    float* out = (float*)d_out;
    float* ws  = (float*)d_ws;

    rbf_precompute<<<1, 64, 0, stream>>>(sf, vf, ws);

    const int grid = (PN * PM) / 256;   // 16,384 blocks, one per 256 pairs
    rbf_all_kernel<<<grid, 256, 0, stream>>>(x, xx, ws, out);
}